// Round 3
// baseline (459.407 us; speedup 1.0000x reference)
//
#include <hip/hip_runtime.h>
#include <hip/hip_bf16.h>
#include <stdint.h>

// ---------------- types / helpers ----------------
typedef __attribute__((ext_vector_type(8))) short bf16x8;   // 8 bf16 = 4 VGPRs
typedef __attribute__((ext_vector_type(4))) float f32x4;

__device__ __forceinline__ unsigned short f2bf(float f) {
  unsigned int u = __float_as_uint(f);
  u += 0x7fff + ((u >> 16) & 1);   // round-to-nearest-even
  return (unsigned short)(u >> 16);
}

__device__ __forceinline__ void gload16(const void* g, void* l) {
  __builtin_amdgcn_global_load_lds(
      (const __attribute__((address_space(1))) void*)g,
      (__attribute__((address_space(3))) void*)l, 16, 0, 0);
}

// ---------------- problem constants ----------------
#define Bsz   8192
#define D_IN  1024
#define D_H   2048
#define D_BOT 512
#define D_EXP 1024
#define N_CLS 10

// ---------------- small utility kernels ----------------
__global__ void k_zero_meta(int* cnt, int* cur) {
  int t = threadIdx.x;
  if (t < N_CLS) { cnt[t] = 0; cur[t] = 0; }
}

__global__ void k_hist(const int* __restrict__ lab, int* cnt) {
  int b = blockIdx.x * blockDim.x + threadIdx.x;
  atomicAdd(&cnt[lab[b]], 1);
}

__global__ void k_scan(const int* __restrict__ cnt, int* start) {
  if (threadIdx.x == 0) {
    int s = 0;
    for (int e = 0; e < N_CLS; e++) { start[e] = s; s += cnt[e]; }
  }
}

__global__ void k_assign(const int* __restrict__ lab, const int* __restrict__ start,
                         int* cur, int* perm) {
  int b = blockIdx.x * blockDim.x + threadIdx.x;
  int l = lab[b];
  int p = atomicAdd(&cur[l], 1);
  perm[start[l] + p] = b;
}

// fp32 -> bf16 elementwise (8 elems/thread), n divisible by 8*blockDim*gridDim
__global__ void k_cvt(const float* __restrict__ in, unsigned short* __restrict__ out) {
  int i = (blockIdx.x * blockDim.x + threadIdx.x) * 8;
  const float4* p = (const float4*)(in + i);
  float4 a = p[0], b = p[1];
  uint4 o;
  o.x = (unsigned)f2bf(a.x) | ((unsigned)f2bf(a.y) << 16);
  o.y = (unsigned)f2bf(a.z) | ((unsigned)f2bf(a.w) << 16);
  o.z = (unsigned)f2bf(b.x) | ((unsigned)f2bf(b.y) << 16);
  o.w = (unsigned)f2bf(b.z) | ((unsigned)f2bf(b.w) << 16);
  *(uint4*)(out + i) = o;
}

// W [K][N] fp32  ->  WT [N][K] bf16   (tiled transpose; K,N multiples of 32)
__global__ void k_transpose_cvt(const float* __restrict__ in, unsigned short* __restrict__ out,
                                int K, int N) {
  __shared__ float tile[32][33];
  size_t eoff = (size_t)blockIdx.z * K * N;
  in  += eoff;
  out += eoff;
  int n0 = blockIdx.x * 32, k0 = blockIdx.y * 32;
  int tx = threadIdx.x, ty = threadIdx.y;   // 32 x 8
#pragma unroll
  for (int i = 0; i < 4; i++) {
    int k = ty + i * 8;
    tile[k][tx] = in[(size_t)(k0 + k) * N + n0 + tx];
  }
  __syncthreads();
#pragma unroll
  for (int i = 0; i < 4; i++) {
    int n = ty + i * 8;
    out[(size_t)(n0 + n) * K + k0 + tx] = f2bf(tile[tx][n]);
  }
}

// h2p[r][:] = h2[perm[r]][:]   (bf16, D_BOT cols, 8 elems/thread)
__global__ void k_gather(const unsigned short* __restrict__ h2, const int* __restrict__ perm,
                         unsigned short* __restrict__ h2p) {
  int tid = blockIdx.x * blockDim.x + threadIdx.x;
  int row = tid >> 6;
  int j = (tid & 63) * 8;
  int src = perm[row];
  *(uint4*)(h2p + (size_t)row * D_BOT + j) =
      *(const uint4*)(h2 + (size_t)src * D_BOT + j);
}

// ---------------- GEMM: C = act(A[M,K]bf16 * WT[N,K]bf16^T + bias) ----------------
#define BM 128
#define BN 128
#define BK 32

template <bool RELU, bool BF16OUT, bool GROUPED, bool SCATTER>
__global__ __launch_bounds__(256) void k_gemm(
    const unsigned short* __restrict__ A,   // [M][K] bf16 (grouped: rows start at starts[e])
    const unsigned short* __restrict__ WT,  // [N][K] bf16 (grouped: + e*N*K)
    const float* __restrict__ bias,         // [N]        (grouped: + e*N)
    void* __restrict__ Cv,                  // [Mout][N] bf16 or fp32
    int M, int N, int K,
    const int* __restrict__ starts, const int* __restrict__ counts,
    const int* __restrict__ perm) {
  int Meff = M, start = 0;
  int m0 = blockIdx.x * BM;
  if (GROUPED) {
    int e = blockIdx.z;
    start = starts[e];
    Meff  = counts[e];
    if (m0 >= Meff) return;
    A    += (size_t)start * K;
    WT   += (size_t)e * N * K;
    bias += (size_t)e * N;
  }
  int n0 = blockIdx.y * BN;

  __shared__ __align__(16) unsigned short As[BM * BK];
  __shared__ __align__(16) unsigned short Bs[BN * BK];

  const int t = threadIdx.x;
  const int l = t & 63;
  const int w = t >> 6;
  const int wm = (w >> 1) * 64;
  const int wn = (w & 1) * 64;

  // staging coordinates: thread t loads 16B at tile row (t>>2)+q*64, col (t&3)*8
  const int srow = t >> 2;
  const int scol = (t & 3) * 8;
  int ar0 = m0 + srow, ar1 = m0 + srow + 64;
  if (GROUPED) {
    ar0 = ar0 < Meff ? ar0 : Meff - 1;
    ar1 = ar1 < Meff ? ar1 : Meff - 1;
  }
  const unsigned short* agp0 = A + (size_t)ar0 * K + scol;
  const unsigned short* agp1 = A + (size_t)ar1 * K + scol;
  const unsigned short* bgp0 = WT + (size_t)(n0 + srow) * K + scol;
  const unsigned short* bgp1 = WT + (size_t)(n0 + srow + 64) * K + scol;

  f32x4 acc[4][4] = {};

  for (int k0 = 0; k0 < K; k0 += BK) {
    gload16(agp0, As + t * 8);
    gload16(agp1, As + t * 8 + 2048);
    gload16(bgp0, Bs + t * 8);
    gload16(bgp1, Bs + t * 8 + 2048);
    agp0 += BK; agp1 += BK; bgp0 += BK; bgp1 += BK;
    __syncthreads();   // compiler drains vmcnt before s_barrier

    bf16x8 af[4], bfr[4];
#pragma unroll
    for (int i = 0; i < 4; i++)
      af[i] = *(const bf16x8*)(As + (wm + i * 16 + (l & 15)) * BK + (l >> 4) * 8);
#pragma unroll
    for (int i = 0; i < 4; i++)
      bfr[i] = *(const bf16x8*)(Bs + (wn + i * 16 + (l & 15)) * BK + (l >> 4) * 8);
#pragma unroll
    for (int mi = 0; mi < 4; mi++)
#pragma unroll
      for (int ni = 0; ni < 4; ni++)
        acc[mi][ni] = __builtin_amdgcn_mfma_f32_16x16x32_bf16(af[mi], bfr[ni], acc[mi][ni], 0, 0, 0);
    __syncthreads();   // LDS safe to overwrite next iter
  }

  // epilogue: C row = (l>>4)*4 + j (+16*mi), col = (l&15) (+16*ni)
  const int cb = n0 + wn + (l & 15);
#pragma unroll
  for (int ni = 0; ni < 4; ni++) {
    int c = cb + ni * 16;
    float bv = bias[c];
#pragma unroll
    for (int mi = 0; mi < 4; mi++) {
#pragma unroll
      for (int j = 0; j < 4; j++) {
        int r = m0 + wm + mi * 16 + ((l >> 4) << 2) + j;
        if (GROUPED && r >= Meff) continue;
        float v = acc[mi][ni][j] + bv;
        if (RELU) v = fmaxf(v, 0.0f);
        int orow;
        if (SCATTER)      orow = perm[start + r];
        else if (GROUPED) orow = start + r;
        else              orow = r;
        if (BF16OUT) ((unsigned short*)Cv)[(size_t)orow * N + c] = f2bf(v);
        else         ((float*)Cv)[(size_t)orow * N + c] = v;
      }
    }
  }
}

// ---------------- launch ----------------
extern "C" void kernel_launch(void* const* d_in, const int* in_sizes, int n_in,
                              void* d_out, int out_size, void* d_ws, size_t ws_size,
                              hipStream_t stream) {
  const float* x      = (const float*)d_in[0];
  const int*   labels = (const int*)d_in[1];
  const float* W1  = (const float*)d_in[2];  const float* b1  = (const float*)d_in[3];
  const float* W2  = (const float*)d_in[4];  const float* b2  = (const float*)d_in[5];
  const float* EW1 = (const float*)d_in[6];  const float* Eb1 = (const float*)d_in[7];
  const float* EW2 = (const float*)d_in[8];  const float* Eb2 = (const float*)d_in[9];
  const float* DW1 = (const float*)d_in[10]; const float* Db1 = (const float*)d_in[11];
  const float* DW2 = (const float*)d_in[12]; const float* Db2 = (const float*)d_in[13];
  float* out = (float*)d_out;

  char* ws = (char*)d_ws;
  size_t o = 0;
  unsigned short* W1T  = (unsigned short*)(ws + o); o += (size_t)D_IN * D_H * 2;           // 4MB
  unsigned short* W2T  = (unsigned short*)(ws + o); o += (size_t)D_H * D_BOT * 2;          // 2MB
  unsigned short* EW1T = (unsigned short*)(ws + o); o += (size_t)N_CLS * D_BOT * D_EXP * 2;// 10MB
  unsigned short* EW2T = (unsigned short*)(ws + o); o += (size_t)N_CLS * D_EXP * D_BOT * 2;// 10MB
  unsigned short* DW1T = (unsigned short*)(ws + o); o += (size_t)D_BOT * D_H * 2;          // 2MB
  unsigned short* DW2T = (unsigned short*)(ws + o); o += (size_t)D_H * D_IN * 2;           // 4MB
  unsigned short* xb   = (unsigned short*)(ws + o); o += (size_t)Bsz * D_IN * 2;           // 16MB (reused as e1p)
  unsigned short* e1p  = xb;                                                               // alias: xb dead after L1
  unsigned short* actA = (unsigned short*)(ws + o); o += (size_t)Bsz * D_H * 2;            // 32MB (h1, later d)
  unsigned short* h2   = (unsigned short*)(ws + o); o += (size_t)Bsz * D_BOT * 2;          // 8MB
  unsigned short* h2p  = (unsigned short*)(ws + o); o += (size_t)Bsz * D_BOT * 2;          // 8MB
  unsigned short* sel  = (unsigned short*)(ws + o); o += (size_t)Bsz * D_BOT * 2;          // 8MB
  int* counts = (int*)(ws + o);
  int* starts = counts + 16;
  int* cursor = counts + 32;
  int* perm   = counts + 64;

  // routing metadata
  k_zero_meta<<<1, 64, 0, stream>>>(counts, cursor);
  k_hist<<<Bsz / 256, 256, 0, stream>>>(labels, counts);
  k_scan<<<1, 64, 0, stream>>>(counts, starts);
  k_assign<<<Bsz / 256, 256, 0, stream>>>(labels, starts, cursor, perm);

  // conversions
  k_cvt<<<(Bsz * D_IN) / (256 * 8), 256, 0, stream>>>(x, xb);
  k_transpose_cvt<<<dim3(D_H / 32, D_IN / 32, 1),  dim3(32, 8), 0, stream>>>(W1, W1T, D_IN, D_H);
  k_transpose_cvt<<<dim3(D_BOT / 32, D_H / 32, 1), dim3(32, 8), 0, stream>>>(W2, W2T, D_H, D_BOT);
  k_transpose_cvt<<<dim3(D_EXP / 32, D_BOT / 32, N_CLS), dim3(32, 8), 0, stream>>>(EW1, EW1T, D_BOT, D_EXP);
  k_transpose_cvt<<<dim3(D_BOT / 32, D_EXP / 32, N_CLS), dim3(32, 8), 0, stream>>>(EW2, EW2T, D_EXP, D_BOT);
  k_transpose_cvt<<<dim3(D_H / 32, D_BOT / 32, 1), dim3(32, 8), 0, stream>>>(DW1, DW1T, D_BOT, D_H);
  k_transpose_cvt<<<dim3(D_IN / 32, D_H / 32, 1),  dim3(32, 8), 0, stream>>>(DW2, DW2T, D_H, D_IN);

  // encoder
  k_gemm<true, true, false, false><<<dim3(Bsz / BM, D_H / BN), 256, 0, stream>>>(
      xb, W1T, b1, actA, Bsz, D_H, D_IN, nullptr, nullptr, nullptr);
  k_gemm<true, true, false, false><<<dim3(Bsz / BM, D_BOT / BN), 256, 0, stream>>>(
      actA, W2T, b2, h2, Bsz, D_BOT, D_H, nullptr, nullptr, nullptr);

  // gather rows into class-contiguous order
  k_gather<<<(Bsz * 64) / 256, 256, 0, stream>>>(h2, perm, h2p);

  // routed experts (grouped GEMMs); E1 writes permuted order, E2 scatters back
  k_gemm<true, true, true, false><<<dim3(Bsz / BM, D_EXP / BN, N_CLS), 256, 0, stream>>>(
      h2p, EW1T, Eb1, e1p, Bsz, D_EXP, D_BOT, starts, counts, nullptr);
  k_gemm<true, true, true, true><<<dim3(Bsz / BM, D_BOT / BN, N_CLS), 256, 0, stream>>>(
      e1p, EW2T, Eb2, sel, Bsz, D_BOT, D_EXP, starts, counts, perm);

  // decoder
  k_gemm<true, true, false, false><<<dim3(Bsz / BM, D_H / BN), 256, 0, stream>>>(
      sel, DW1T, Db1, actA, Bsz, D_H, D_BOT, nullptr, nullptr, nullptr);
  k_gemm<false, false, false, false><<<dim3(Bsz / BM, D_IN / BN), 256, 0, stream>>>(
      actA, DW2T, Db2, out, Bsz, D_IN, D_H, nullptr, nullptr, nullptr);
}

// Round 4
// 312.463 us; speedup vs baseline: 1.4703x; 1.4703x over previous
//
#include <hip/hip_runtime.h>
#include <hip/hip_bf16.h>
#include <stdint.h>

// ---------------- types / helpers ----------------
typedef __attribute__((ext_vector_type(8))) short bf16x8;   // 8 bf16 = 4 VGPRs
typedef __attribute__((ext_vector_type(4))) float f32x4;

__device__ __forceinline__ unsigned short f2bf(float f) {
  unsigned int u = __float_as_uint(f);
  u += 0x7fff + ((u >> 16) & 1);   // round-to-nearest-even
  return (unsigned short)(u >> 16);
}

__device__ __forceinline__ void gload16(const void* g, void* l) {
  __builtin_amdgcn_global_load_lds(
      (const __attribute__((address_space(1))) void*)g,
      (__attribute__((address_space(3))) void*)l, 16, 0, 0);
}

// ---------------- problem constants ----------------
#define Bsz   8192
#define D_IN  1024
#define D_H   2048
#define D_BOT 512
#define D_EXP 1024
#define N_CLS 10

// ---------------- small utility kernels ----------------
__global__ void k_zero_meta(int* cnt, int* cur) {
  int t = threadIdx.x;
  if (t < N_CLS) { cnt[t] = 0; cur[t] = 0; }
}

__global__ void k_hist(const int* __restrict__ lab, int* cnt) {
  int b = blockIdx.x * blockDim.x + threadIdx.x;
  atomicAdd(&cnt[lab[b]], 1);
}

__global__ void k_scan(const int* __restrict__ cnt, int* start) {
  if (threadIdx.x == 0) {
    int s = 0;
    for (int e = 0; e < N_CLS; e++) { start[e] = s; s += cnt[e]; }
  }
}

__global__ void k_assign(const int* __restrict__ lab, const int* __restrict__ start,
                         int* cur, int* perm) {
  int b = blockIdx.x * blockDim.x + threadIdx.x;
  int l = lab[b];
  int p = atomicAdd(&cur[l], 1);
  perm[start[l] + p] = b;
}

// fp32 -> bf16 elementwise (8 elems/thread)
__global__ void k_cvt(const float* __restrict__ in, unsigned short* __restrict__ out) {
  int i = (blockIdx.x * blockDim.x + threadIdx.x) * 8;
  const float4* p = (const float4*)(in + i);
  float4 a = p[0], b = p[1];
  uint4 o;
  o.x = (unsigned)f2bf(a.x) | ((unsigned)f2bf(a.y) << 16);
  o.y = (unsigned)f2bf(a.z) | ((unsigned)f2bf(a.w) << 16);
  o.z = (unsigned)f2bf(b.x) | ((unsigned)f2bf(b.y) << 16);
  o.w = (unsigned)f2bf(b.z) | ((unsigned)f2bf(b.w) << 16);
  *(uint4*)(out + i) = o;
}

// W [K][N] fp32  ->  WT [N][K] bf16   (tiled transpose; K,N multiples of 32)
__global__ void k_transpose_cvt(const float* __restrict__ in, unsigned short* __restrict__ out,
                                int K, int N) {
  __shared__ float tile[32][33];
  size_t eoff = (size_t)blockIdx.z * K * N;
  in  += eoff;
  out += eoff;
  int n0 = blockIdx.x * 32, k0 = blockIdx.y * 32;
  int tx = threadIdx.x, ty = threadIdx.y;   // 32 x 8
#pragma unroll
  for (int i = 0; i < 4; i++) {
    int k = ty + i * 8;
    tile[k][tx] = in[(size_t)(k0 + k) * N + n0 + tx];
  }
  __syncthreads();
#pragma unroll
  for (int i = 0; i < 4; i++) {
    int n = ty + i * 8;
    out[(size_t)(n0 + n) * K + k0 + tx] = f2bf(tile[tx][n]);
  }
}

// h2p[r][:] = h2[perm[r]][:]
__global__ void k_gather(const unsigned short* __restrict__ h2, const int* __restrict__ perm,
                         unsigned short* __restrict__ h2p) {
  int tid = blockIdx.x * blockDim.x + threadIdx.x;
  int row = tid >> 6;
  int j = (tid & 63) * 8;
  int src = perm[row];
  *(uint4*)(h2p + (size_t)row * D_BOT + j) =
      *(const uint4*)(h2 + (size_t)src * D_BOT + j);
}

// ---------------- GEMM: C = act(A[M,K]bf16 * WT[N,K]bf16^T + bias) ----------------
// Double-buffered LDS, one barrier per K-step (loads for t+1 in flight across
// the compute of t; __syncthreads' vmcnt(0) drain lands AFTER the MFMA phase).
// XCD chunk-swizzled flat block id, y-fastest work order.
// GROUPED: grid.x covers worst-case sum of per-expert block counts; device-side
// prefix over counts[] maps bx -> (expert, m-offset). All blocks active.

template <int TBM, int TBN, int WM, int WN, bool RELU, bool BF16OUT, bool GROUPED, bool SCATTER>
__global__ __launch_bounds__(256) void k_gemm(
    const unsigned short* __restrict__ A,   // [M][K] bf16 (grouped: + starts[e]*K)
    const unsigned short* __restrict__ WT,  // [N][K] bf16 (grouped: + e*N*K)
    const float* __restrict__ bias,         // [N]        (grouped: + e*N)
    void* __restrict__ Cv,                  // [Mout][N] bf16 or fp32
    int M, int N, int K,
    const int* __restrict__ starts, const int* __restrict__ counts,
    const int* __restrict__ perm) {
  constexpr int FM = TBM / WM / 16;       // frag repeats in M per wave
  constexpr int FN = TBN / WN / 16;       // frag repeats in N per wave
  constexpr int ALOADS = TBM / 64;        // 16B stage loads per thread for A
  constexpr int BLOADS = TBN / 64;

  // --- XCD-bijective chunk swizzle (m204), y-fastest work order ---
  const int nby = gridDim.y;
  const int nwg = gridDim.x * nby;
  int orig = blockIdx.x + gridDim.x * blockIdx.y;   // dispatch order (x fastest)
  int q = nwg >> 3, r = nwg & 7;
  int xcd = orig & 7, idx = orig >> 3;
  int wg = (xcd < r ? xcd * (q + 1) : r * (q + 1) + (xcd - r) * q) + idx;
  int bx = wg / nby, by = wg % nby;       // consecutive wg: same bx, adjacent by

  int Meff, start = 0, mo;
  const unsigned short* Wp = WT;
  const float* biasp = bias;
  if (GROUPED) {
    int bxr = bx;
    int found = 0;
#pragma unroll
    for (int e = 0; e < N_CLS; ++e) {
      int c = counts[e];
      int nb = (c + TBM - 1) / TBM;
      if (!found && bxr < nb) {
        found = 1; Meff = c; start = starts[e]; mo = bxr * TBM;
        Wp = WT + (size_t)e * N * K; biasp = bias + (size_t)e * N;
      }
      if (!found) bxr -= nb;
    }
    if (!found) return;
    A += (size_t)start * K;
  } else {
    Meff = M; mo = bx * TBM;
  }
  const int n0 = by * TBN;

  __shared__ __align__(16) unsigned short As[2][TBM * 32];
  __shared__ __align__(16) unsigned short Bs[2][TBN * 32];

  const int t = threadIdx.x;
  const int l = t & 63;
  const int w = t >> 6;
  const int wm = (w / WN) * (TBM / WM);
  const int wn = (w % WN) * (TBN / WN);

  // staging coords: thread t stages 16B at tile row (t>>2)+i*64, col (t&3)*8
  const int srow = t >> 2;
  const int scol = (t & 3) * 8;
  const unsigned short* ag[ALOADS];
  const unsigned short* bg[BLOADS];
#pragma unroll
  for (int i = 0; i < ALOADS; ++i) {
    int arow = mo + srow + i * 64;
    if (GROUPED) arow = arow < Meff ? arow : Meff - 1;
    ag[i] = A + (size_t)arow * K + scol;
  }
#pragma unroll
  for (int i = 0; i < BLOADS; ++i)
    bg[i] = Wp + (size_t)(n0 + srow + i * 64) * K + scol;

  auto STAGE = [&](int buf) {
#pragma unroll
    for (int i = 0; i < ALOADS; ++i) {
      gload16(ag[i], &As[buf][t * 8 + i * 2048]);
      ag[i] += 32;
    }
#pragma unroll
    for (int i = 0; i < BLOADS; ++i) {
      gload16(bg[i], &Bs[buf][t * 8 + i * 2048]);
      bg[i] += 32;
    }
  };

  f32x4 acc[FM][FN] = {};

  const int nt = K / 32;
  STAGE(0);
  __syncthreads();                       // drains vmcnt(0): tile 0 ready
  int cur = 0;
  for (int tI = 0; tI < nt; ++tI) {
    if (tI + 1 < nt) STAGE(cur ^ 1);     // next tile's loads in flight over compute

    bf16x8 af[FM], bfr[FN];
#pragma unroll
    for (int i = 0; i < FM; ++i)
      af[i] = *(const bf16x8*)(&As[cur][(wm + i * 16 + (l & 15)) * 32 + (l >> 4) * 8]);
#pragma unroll
    for (int i = 0; i < FN; ++i)
      bfr[i] = *(const bf16x8*)(&Bs[cur][(wn + i * 16 + (l & 15)) * 32 + (l >> 4) * 8]);
#pragma unroll
    for (int mi = 0; mi < FM; ++mi)
#pragma unroll
      for (int ni = 0; ni < FN; ++ni)
        acc[mi][ni] = __builtin_amdgcn_mfma_f32_16x16x32_bf16(af[mi], bfr[ni], acc[mi][ni], 0, 0, 0);

    __syncthreads();                     // vmcnt(0): tile t+1 landed; cur buf free
    cur ^= 1;
  }

  // epilogue: C row = wm + mi*16 + (l>>4)*4 + j, col = wn + (l&15) + ni*16
  const int cb = n0 + wn + (l & 15);
#pragma unroll
  for (int ni = 0; ni < FN; ++ni) {
    int c = cb + ni * 16;
    float bv = biasp[c];
#pragma unroll
    for (int mi = 0; mi < FM; ++mi) {
#pragma unroll
      for (int j = 0; j < 4; ++j) {
        int rl = wm + mi * 16 + ((l >> 4) << 2) + j;   // row within tile
        int re = mo + rl;                               // row within expert / M
        if (GROUPED && re >= Meff) continue;
        float v = acc[mi][ni][j] + bv;
        if (RELU) v = fmaxf(v, 0.0f);
        int orow;
        if (SCATTER)      orow = perm[start + re];
        else if (GROUPED) orow = start + re;
        else              orow = re;
        if (BF16OUT) ((unsigned short*)Cv)[(size_t)orow * N + c] = f2bf(v);
        else         ((float*)Cv)[(size_t)orow * N + c] = v;
      }
    }
  }
}

#define GX_GROUPED 74   // worst-case sum of ceil(counts[e]/128) over 10 experts

// ---------------- launch ----------------
extern "C" void kernel_launch(void* const* d_in, const int* in_sizes, int n_in,
                              void* d_out, int out_size, void* d_ws, size_t ws_size,
                              hipStream_t stream) {
  const float* x      = (const float*)d_in[0];
  const int*   labels = (const int*)d_in[1];
  const float* W1  = (const float*)d_in[2];  const float* b1  = (const float*)d_in[3];
  const float* W2  = (const float*)d_in[4];  const float* b2  = (const float*)d_in[5];
  const float* EW1 = (const float*)d_in[6];  const float* Eb1 = (const float*)d_in[7];
  const float* EW2 = (const float*)d_in[8];  const float* Eb2 = (const float*)d_in[9];
  const float* DW1 = (const float*)d_in[10]; const float* Db1 = (const float*)d_in[11];
  const float* DW2 = (const float*)d_in[12]; const float* Db2 = (const float*)d_in[13];
  float* out = (float*)d_out;

  char* ws = (char*)d_ws;
  size_t o = 0;
  unsigned short* W1T  = (unsigned short*)(ws + o); o += (size_t)D_IN * D_H * 2;
  unsigned short* W2T  = (unsigned short*)(ws + o); o += (size_t)D_H * D_BOT * 2;
  unsigned short* EW1T = (unsigned short*)(ws + o); o += (size_t)N_CLS * D_BOT * D_EXP * 2;
  unsigned short* EW2T = (unsigned short*)(ws + o); o += (size_t)N_CLS * D_EXP * D_BOT * 2;
  unsigned short* DW1T = (unsigned short*)(ws + o); o += (size_t)D_BOT * D_H * 2;
  unsigned short* DW2T = (unsigned short*)(ws + o); o += (size_t)D_H * D_IN * 2;
  unsigned short* xb   = (unsigned short*)(ws + o); o += (size_t)Bsz * D_IN * 2;
  unsigned short* e1p  = xb;                         // alias: xb dead after L1
  unsigned short* actA = (unsigned short*)(ws + o); o += (size_t)Bsz * D_H * 2;
  unsigned short* h2   = (unsigned short*)(ws + o); o += (size_t)Bsz * D_BOT * 2;
  unsigned short* h2p  = (unsigned short*)(ws + o); o += (size_t)Bsz * D_BOT * 2;
  unsigned short* sel  = (unsigned short*)(ws + o); o += (size_t)Bsz * D_BOT * 2;
  int* counts = (int*)(ws + o);
  int* starts = counts + 16;
  int* cursor = counts + 32;
  int* perm   = counts + 64;

  // routing metadata
  k_zero_meta<<<1, 64, 0, stream>>>(counts, cursor);
  k_hist<<<Bsz / 256, 256, 0, stream>>>(labels, counts);
  k_scan<<<1, 64, 0, stream>>>(counts, starts);
  k_assign<<<Bsz / 256, 256, 0, stream>>>(labels, starts, cursor, perm);

  // conversions
  k_cvt<<<(Bsz * D_IN) / (256 * 8), 256, 0, stream>>>(x, xb);
  k_transpose_cvt<<<dim3(D_H / 32, D_IN / 32, 1),  dim3(32, 8), 0, stream>>>(W1, W1T, D_IN, D_H);
  k_transpose_cvt<<<dim3(D_BOT / 32, D_H / 32, 1), dim3(32, 8), 0, stream>>>(W2, W2T, D_H, D_BOT);
  k_transpose_cvt<<<dim3(D_EXP / 32, D_BOT / 32, N_CLS), dim3(32, 8), 0, stream>>>(EW1, EW1T, D_BOT, D_EXP);
  k_transpose_cvt<<<dim3(D_BOT / 32, D_EXP / 32, N_CLS), dim3(32, 8), 0, stream>>>(EW2, EW2T, D_EXP, D_BOT);
  k_transpose_cvt<<<dim3(D_H / 32, D_BOT / 32, 1), dim3(32, 8), 0, stream>>>(DW1, DW1T, D_BOT, D_H);
  k_transpose_cvt<<<dim3(D_IN / 32, D_H / 32, 1),  dim3(32, 8), 0, stream>>>(DW2, DW2T, D_H, D_IN);

  // encoder
  k_gemm<128, 128, 2, 2, true, true, false, false><<<dim3(Bsz / 128, D_H / 128), 256, 0, stream>>>(
      xb, W1T, b1, actA, Bsz, D_H, D_IN, nullptr, nullptr, nullptr);
  k_gemm<128, 64, 4, 1, true, true, false, false><<<dim3(Bsz / 128, D_BOT / 64), 256, 0, stream>>>(
      actA, W2T, b2, h2, Bsz, D_BOT, D_H, nullptr, nullptr, nullptr);

  // gather rows into class-contiguous order
  k_gather<<<(Bsz * 64) / 256, 256, 0, stream>>>(h2, perm, h2p);

  // routed experts (compact grouped grids); E1 writes permuted order, E2 scatters back
  k_gemm<128, 128, 2, 2, true, true, true, false><<<dim3(GX_GROUPED, D_EXP / 128), 256, 0, stream>>>(
      h2p, EW1T, Eb1, e1p, Bsz, D_EXP, D_BOT, starts, counts, nullptr);
  k_gemm<128, 64, 4, 1, true, true, true, true><<<dim3(GX_GROUPED, D_BOT / 64), 256, 0, stream>>>(
      e1p, EW2T, Eb2, sel, Bsz, D_BOT, D_EXP, starts, counts, perm);

  // decoder
  k_gemm<128, 128, 2, 2, true, true, false, false><<<dim3(Bsz / 128, D_H / 128), 256, 0, stream>>>(
      sel, DW1T, Db1, actA, Bsz, D_H, D_BOT, nullptr, nullptr, nullptr);
  k_gemm<128, 128, 2, 2, false, false, false, false><<<dim3(Bsz / 128, D_IN / 128), 256, 0, stream>>>(
      actA, DW2T, Db2, out, Bsz, D_IN, D_H, nullptr, nullptr, nullptr);
}

// Round 5
// 265.549 us; speedup vs baseline: 1.7300x; 1.1767x over previous
//
#include <hip/hip_runtime.h>
#include <hip/hip_bf16.h>
#include <stdint.h>

// ---------------- types / helpers ----------------
typedef __attribute__((ext_vector_type(8))) short bf16x8;   // 8 bf16 = 4 VGPRs
typedef __attribute__((ext_vector_type(4))) float f32x4;

__device__ __forceinline__ unsigned short f2bf(float f) {
  unsigned int u = __float_as_uint(f);
  u += 0x7fff + ((u >> 16) & 1);   // round-to-nearest-even
  return (unsigned short)(u >> 16);
}

__device__ __forceinline__ void gload16(const void* g, void* l) {
  __builtin_amdgcn_global_load_lds(
      (const __attribute__((address_space(1))) void*)g,
      (__attribute__((address_space(3))) void*)l, 16, 0, 0);
}

// ---------------- problem constants ----------------
#define Bsz   8192
#define D_IN  1024
#define D_H   2048
#define D_BOT 512
#define D_EXP 1024
#define N_CLS 10

// ---------------- routing: hist + scan + assign in ONE block ----------------
__global__ __launch_bounds__(1024) void k_route(const int* __restrict__ lab,
                                                int* __restrict__ counts,
                                                int* __restrict__ starts,
                                                int* __restrict__ perm) {
  __shared__ int scnt[N_CLS], scur[N_CLS];
  const int t = threadIdx.x;
  if (t < N_CLS) scnt[t] = 0;
  __syncthreads();
  int myl[8];
#pragma unroll
  for (int i = 0; i < 8; ++i) {
    myl[i] = lab[t * 8 + i];
    atomicAdd(&scnt[myl[i]], 1);
  }
  __syncthreads();
  if (t == 0) {
    int s = 0;
    for (int e = 0; e < N_CLS; ++e) {
      starts[e] = s; scur[e] = s; counts[e] = scnt[e]; s += scnt[e];
    }
  }
  __syncthreads();
#pragma unroll
  for (int i = 0; i < 8; ++i) {
    int p = atomicAdd(&scur[myl[i]], 1);
    perm[p] = t * 8 + i;
  }
}

// fp32 -> bf16 elementwise (8 elems/thread)
__global__ void k_cvt(const float* __restrict__ in, unsigned short* __restrict__ out) {
  int i = (blockIdx.x * blockDim.x + threadIdx.x) * 8;
  const float4* p = (const float4*)(in + i);
  float4 a = p[0], b = p[1];
  uint4 o;
  o.x = (unsigned)f2bf(a.x) | ((unsigned)f2bf(a.y) << 16);
  o.y = (unsigned)f2bf(a.z) | ((unsigned)f2bf(a.w) << 16);
  o.z = (unsigned)f2bf(b.x) | ((unsigned)f2bf(b.y) << 16);
  o.w = (unsigned)f2bf(b.z) | ((unsigned)f2bf(b.w) << 16);
  *(uint4*)(out + i) = o;
}

// W [K][N] fp32  ->  WT [N][K] bf16   (tiled transpose; K,N multiples of 32)
__global__ void k_transpose_cvt(const float* __restrict__ in, unsigned short* __restrict__ out,
                                int K, int N) {
  __shared__ float tile[32][33];
  size_t eoff = (size_t)blockIdx.z * K * N;
  in  += eoff;
  out += eoff;
  int n0 = blockIdx.x * 32, k0 = blockIdx.y * 32;
  int tx = threadIdx.x, ty = threadIdx.y;   // 32 x 8
#pragma unroll
  for (int i = 0; i < 4; i++) {
    int k = ty + i * 8;
    tile[k][tx] = in[(size_t)(k0 + k) * N + n0 + tx];
  }
  __syncthreads();
#pragma unroll
  for (int i = 0; i < 4; i++) {
    int n = ty + i * 8;
    out[(size_t)(n0 + n) * K + k0 + tx] = f2bf(tile[tx][n]);
  }
}

// ---------------- GEMM: C = act(A[M,K]bf16 * WT[N,K]bf16^T + bias) ----------------
// Triple-buffered LDS, depth-2 prefetch, counted vmcnt (never 0 mid-loop),
// one raw s_barrier per K-step. Per iter: wait(tile t) -> barrier ->
// stage(tile t+2) -> ds_read/MFMA(tile t). Loads get ~2 compute phases to land.
// GATHER: A rows indexed via perm[start+row] (fuses row gather into staging).

template <int TBM, int TBN, int WM, int WN,
          bool RELU, bool BF16OUT, bool GROUPED, bool SCATTER, bool GATHER>
__global__ __launch_bounds__(256) void k_gemm(
    const unsigned short* __restrict__ A,   // [M][K] bf16
    const unsigned short* __restrict__ WT,  // [N][K] bf16 (grouped: + e*N*K)
    const float* __restrict__ bias,         // [N]        (grouped: + e*N)
    void* __restrict__ Cv,                  // [Mout][N] bf16 or fp32
    int M, int N, int K,
    const int* __restrict__ starts, const int* __restrict__ counts,
    const int* __restrict__ perm) {
  constexpr int FM = TBM / WM / 16;
  constexpr int FN = TBN / WN / 16;
  constexpr int ALOADS = TBM / 64;
  constexpr int BLOADS = TBN / 64;
  constexpr int LDS_LD = ALOADS + BLOADS;   // stage loads per thread per tile

  // --- XCD-bijective chunk swizzle (m204), y-fastest work order ---
  const int nby = gridDim.y;
  const int nwg = gridDim.x * nby;
  int orig = blockIdx.x + gridDim.x * blockIdx.y;
  int q = nwg >> 3, r = nwg & 7;
  int xcd = orig & 7, idx = orig >> 3;
  int wg = (xcd < r ? xcd * (q + 1) : r * (q + 1) + (xcd - r) * q) + idx;
  int bx = wg / nby, by = wg % nby;

  int Meff, start = 0, mo;
  const unsigned short* Wp = WT;
  const float* biasp = bias;
  if (GROUPED) {
    int bxr = bx;
    int found = 0;
#pragma unroll
    for (int e = 0; e < N_CLS; ++e) {
      int c = counts[e];
      int nb = (c + TBM - 1) / TBM;
      if (!found && bxr < nb) {
        found = 1; Meff = c; start = starts[e]; mo = bxr * TBM;
        Wp = WT + (size_t)e * N * K; biasp = bias + (size_t)e * N;
      }
      if (!found) bxr -= nb;
    }
    if (!found) return;
    if (!GATHER) A += (size_t)start * K;
  } else {
    Meff = M; mo = bx * TBM;
  }
  const int n0 = by * TBN;

  __shared__ __align__(16) unsigned short As[3][TBM * 32];
  __shared__ __align__(16) unsigned short Bs[3][TBN * 32];

  const int t = threadIdx.x;
  const int l = t & 63;
  const int w = t >> 6;
  const int wm = (w / WN) * (TBM / WM);
  const int wn = (w % WN) * (TBN / WN);

  // staging coords: thread t stages 16B at tile row (t>>2)+i*64, col (t&3)*8
  const int srow = t >> 2;
  const int scol = (t & 3) * 8;
  const unsigned short* ag[ALOADS];
  const unsigned short* bg[BLOADS];
#pragma unroll
  for (int i = 0; i < ALOADS; ++i) {
    int arow = mo + srow + i * 64;
    if (GROUPED) arow = arow < Meff ? arow : Meff - 1;
    int srcrow = GATHER ? perm[start + arow] : arow;
    ag[i] = A + (size_t)srcrow * K + scol;
  }
#pragma unroll
  for (int i = 0; i < BLOADS; ++i)
    bg[i] = Wp + (size_t)(n0 + srow + i * 64) * K + scol;

  auto STAGE = [&](int buf) {
#pragma unroll
    for (int i = 0; i < ALOADS; ++i) {
      gload16(ag[i], &As[buf][t * 8 + i * 2048]);
      ag[i] += 32;
    }
#pragma unroll
    for (int i = 0; i < BLOADS; ++i) {
      gload16(bg[i], &Bs[buf][t * 8 + i * 2048]);
      bg[i] += 32;
    }
  };

  f32x4 acc[FM][FN] = {};

  const int nt = K / 32;   // >= 16 for all our shapes
  STAGE(0);
  STAGE(1);
  for (int tI = 0; tI < nt; ++tI) {
    // wait: this wave's tile-t loads done (tolerate t+1's LDS_LD in flight)
    if (tI + 1 < nt)
      asm volatile("s_waitcnt vmcnt(%0)" :: "i"(LDS_LD) : "memory");
    else
      asm volatile("s_waitcnt vmcnt(0)" ::: "memory");
    __builtin_amdgcn_s_barrier();          // all waves: tile t ready; prev reads done
    __builtin_amdgcn_sched_barrier(0);
    if (tI + 2 < nt) STAGE((tI + 2) % 3);  // overwrites buf read at t-1: safe post-barrier

    const int cur = tI % 3;
    bf16x8 af[FM], bfr[FN];
#pragma unroll
    for (int i = 0; i < FM; ++i)
      af[i] = *(const bf16x8*)(&As[cur][(wm + i * 16 + (l & 15)) * 32 + (l >> 4) * 8]);
#pragma unroll
    for (int i = 0; i < FN; ++i)
      bfr[i] = *(const bf16x8*)(&Bs[cur][(wn + i * 16 + (l & 15)) * 32 + (l >> 4) * 8]);
#pragma unroll
    for (int mi = 0; mi < FM; ++mi)
#pragma unroll
      for (int ni = 0; ni < FN; ++ni)
        acc[mi][ni] = __builtin_amdgcn_mfma_f32_16x16x32_bf16(af[mi], bfr[ni], acc[mi][ni], 0, 0, 0);
  }

  // epilogue: C row = wm + mi*16 + (l>>4)*4 + j, col = wn + (l&15) + ni*16
  const int cb = n0 + wn + (l & 15);
#pragma unroll
  for (int ni = 0; ni < FN; ++ni) {
    int c = cb + ni * 16;
    float bv = biasp[c];
#pragma unroll
    for (int mi = 0; mi < FM; ++mi) {
#pragma unroll
      for (int j = 0; j < 4; ++j) {
        int rl = wm + mi * 16 + ((l >> 4) << 2) + j;
        int re = mo + rl;
        if (GROUPED && re >= Meff) continue;
        float v = acc[mi][ni][j] + bv;
        if (RELU) v = fmaxf(v, 0.0f);
        int orow;
        if (SCATTER)      orow = perm[start + re];
        else if (GROUPED) orow = start + re;
        else              orow = re;
        if (BF16OUT) ((unsigned short*)Cv)[(size_t)orow * N + c] = f2bf(v);
        else         ((float*)Cv)[(size_t)orow * N + c] = v;
      }
    }
  }
}

#define GX_GROUPED 74   // worst-case sum of ceil(counts[e]/128) over 10 experts

// ---------------- launch ----------------
extern "C" void kernel_launch(void* const* d_in, const int* in_sizes, int n_in,
                              void* d_out, int out_size, void* d_ws, size_t ws_size,
                              hipStream_t stream) {
  const float* x      = (const float*)d_in[0];
  const int*   labels = (const int*)d_in[1];
  const float* W1  = (const float*)d_in[2];  const float* b1  = (const float*)d_in[3];
  const float* W2  = (const float*)d_in[4];  const float* b2  = (const float*)d_in[5];
  const float* EW1 = (const float*)d_in[6];  const float* Eb1 = (const float*)d_in[7];
  const float* EW2 = (const float*)d_in[8];  const float* Eb2 = (const float*)d_in[9];
  const float* DW1 = (const float*)d_in[10]; const float* Db1 = (const float*)d_in[11];
  const float* DW2 = (const float*)d_in[12]; const float* Db2 = (const float*)d_in[13];
  float* out = (float*)d_out;

  char* ws = (char*)d_ws;
  size_t o = 0;
  unsigned short* W1T  = (unsigned short*)(ws + o); o += (size_t)D_IN * D_H * 2;
  unsigned short* W2T  = (unsigned short*)(ws + o); o += (size_t)D_H * D_BOT * 2;
  unsigned short* EW1T = (unsigned short*)(ws + o); o += (size_t)N_CLS * D_BOT * D_EXP * 2;
  unsigned short* EW2T = (unsigned short*)(ws + o); o += (size_t)N_CLS * D_EXP * D_BOT * 2;
  unsigned short* DW1T = (unsigned short*)(ws + o); o += (size_t)D_BOT * D_H * 2;
  unsigned short* DW2T = (unsigned short*)(ws + o); o += (size_t)D_H * D_IN * 2;
  unsigned short* xb   = (unsigned short*)(ws + o); o += (size_t)Bsz * D_IN * 2;
  unsigned short* e1p  = xb;                         // alias: xb dead after L1
  unsigned short* actA = (unsigned short*)(ws + o); o += (size_t)Bsz * D_H * 2;
  unsigned short* h2   = (unsigned short*)(ws + o); o += (size_t)Bsz * D_BOT * 2;
  unsigned short* sel  = (unsigned short*)(ws + o); o += (size_t)Bsz * D_BOT * 2;
  int* counts = (int*)(ws + o);
  int* starts = counts + 16;
  int* perm   = counts + 64;

  // routing metadata (single block)
  k_route<<<1, 1024, 0, stream>>>(labels, counts, starts, perm);

  // conversions
  k_cvt<<<(Bsz * D_IN) / (256 * 8), 256, 0, stream>>>(x, xb);
  k_transpose_cvt<<<dim3(D_H / 32, D_IN / 32, 1),  dim3(32, 8), 0, stream>>>(W1, W1T, D_IN, D_H);
  k_transpose_cvt<<<dim3(D_BOT / 32, D_H / 32, 1), dim3(32, 8), 0, stream>>>(W2, W2T, D_H, D_BOT);
  k_transpose_cvt<<<dim3(D_EXP / 32, D_BOT / 32, N_CLS), dim3(32, 8), 0, stream>>>(EW1, EW1T, D_BOT, D_EXP);
  k_transpose_cvt<<<dim3(D_BOT / 32, D_EXP / 32, N_CLS), dim3(32, 8), 0, stream>>>(EW2, EW2T, D_EXP, D_BOT);
  k_transpose_cvt<<<dim3(D_H / 32, D_BOT / 32, 1), dim3(32, 8), 0, stream>>>(DW1, DW1T, D_BOT, D_H);
  k_transpose_cvt<<<dim3(D_IN / 32, D_H / 32, 1),  dim3(32, 8), 0, stream>>>(DW2, DW2T, D_H, D_IN);

  // encoder
  k_gemm<128, 128, 2, 2, true, true, false, false, false><<<dim3(Bsz / 128, D_H / 128), 256, 0, stream>>>(
      xb, W1T, b1, actA, Bsz, D_H, D_IN, nullptr, nullptr, nullptr);
  k_gemm<128, 64, 4, 1, true, true, false, false, false><<<dim3(Bsz / 128, D_BOT / 64), 256, 0, stream>>>(
      actA, W2T, b2, h2, Bsz, D_BOT, D_H, nullptr, nullptr, nullptr);

  // routed experts; E1 gathers A rows via perm during staging, E2 scatters back
  k_gemm<128, 128, 2, 2, true, true, true, false, true><<<dim3(GX_GROUPED, D_EXP / 128), 256, 0, stream>>>(
      h2, EW1T, Eb1, e1p, Bsz, D_EXP, D_BOT, starts, counts, perm);
  k_gemm<128, 64, 4, 1, true, true, true, true, false><<<dim3(GX_GROUPED, D_BOT / 64), 256, 0, stream>>>(
      e1p, EW2T, Eb2, sel, Bsz, D_BOT, D_EXP, starts, counts, perm);

  // decoder
  k_gemm<128, 128, 2, 2, true, true, false, false, false><<<dim3(Bsz / 128, D_H / 128), 256, 0, stream>>>(
      sel, DW1T, Db1, actA, Bsz, D_H, D_BOT, nullptr, nullptr, nullptr);
  k_gemm<128, 128, 2, 2, false, false, false, false, false><<<dim3(Bsz / 128, D_IN / 128), 256, 0, stream>>>(
      actA, DW2T, Db2, out, Bsz, D_IN, D_H, nullptr, nullptr, nullptr);
}

// Round 6
// 252.535 us; speedup vs baseline: 1.8192x; 1.0515x over previous
//
#include <hip/hip_runtime.h>
#include <hip/hip_bf16.h>
#include <stdint.h>

// ---------------- types / helpers ----------------
typedef __attribute__((ext_vector_type(8))) short bf16x8;   // 8 bf16 = 4 VGPRs
typedef __attribute__((ext_vector_type(4))) float f32x4;

__device__ __forceinline__ unsigned short f2bf(float f) {
  unsigned int u = __float_as_uint(f);
  u += 0x7fff + ((u >> 16) & 1);   // round-to-nearest-even
  return (unsigned short)(u >> 16);
}

__device__ __forceinline__ void gload16(const void* g, void* l) {
  __builtin_amdgcn_global_load_lds(
      (const __attribute__((address_space(1))) void*)g,
      (__attribute__((address_space(3))) void*)l, 16, 0, 0);
}

// ---------------- problem constants ----------------
#define Bsz   8192
#define D_IN  1024
#define D_H   2048
#define D_BOT 512
#define D_EXP 1024
#define N_CLS 10

// ---------------- routing: hist + scan + assign in ONE block ----------------
__global__ __launch_bounds__(1024) void k_route(const int* __restrict__ lab,
                                                int* __restrict__ counts,
                                                int* __restrict__ starts,
                                                int* __restrict__ perm) {
  __shared__ int scnt[N_CLS], scur[N_CLS];
  const int t = threadIdx.x;
  if (t < N_CLS) scnt[t] = 0;
  __syncthreads();
  int myl[8];
#pragma unroll
  for (int i = 0; i < 8; ++i) {
    myl[i] = lab[t * 8 + i];
    atomicAdd(&scnt[myl[i]], 1);
  }
  __syncthreads();
  if (t == 0) {
    int s = 0;
    for (int e = 0; e < N_CLS; ++e) {
      starts[e] = s; scur[e] = s; counts[e] = scnt[e]; s += scnt[e];
    }
  }
  __syncthreads();
#pragma unroll
  for (int i = 0; i < 8; ++i) {
    int p = atomicAdd(&scur[myl[i]], 1);
    perm[p] = t * 8 + i;
  }
}

// fp32 -> bf16 elementwise (8 elems/thread)
__global__ void k_cvt(const float* __restrict__ in, unsigned short* __restrict__ out) {
  int i = (blockIdx.x * blockDim.x + threadIdx.x) * 8;
  const float4* p = (const float4*)(in + i);
  float4 a = p[0], b = p[1];
  uint4 o;
  o.x = (unsigned)f2bf(a.x) | ((unsigned)f2bf(a.y) << 16);
  o.y = (unsigned)f2bf(a.z) | ((unsigned)f2bf(a.w) << 16);
  o.z = (unsigned)f2bf(b.x) | ((unsigned)f2bf(b.y) << 16);
  o.w = (unsigned)f2bf(b.z) | ((unsigned)f2bf(b.w) << 16);
  *(uint4*)(out + i) = o;
}

// W [K][N] fp32  ->  WT [N][K] bf16   (tiled transpose; K,N multiples of 32)
__global__ void k_transpose_cvt(const float* __restrict__ in, unsigned short* __restrict__ out,
                                int K, int N) {
  __shared__ float tile[32][33];
  size_t eoff = (size_t)blockIdx.z * K * N;
  in  += eoff;
  out += eoff;
  int n0 = blockIdx.x * 32, k0 = blockIdx.y * 32;
  int tx = threadIdx.x, ty = threadIdx.y;   // 32 x 8
#pragma unroll
  for (int i = 0; i < 4; i++) {
    int k = ty + i * 8;
    tile[k][tx] = in[(size_t)(k0 + k) * N + n0 + tx];
  }
  __syncthreads();
#pragma unroll
  for (int i = 0; i < 4; i++) {
    int n = ty + i * 8;
    out[(size_t)(n0 + n) * K + k0 + tx] = f2bf(tile[tx][n]);
  }
}

// ============ 8-phase-style GEMM (m201-derived): C = act(A * WT^T + b) ============
// BK=64, 8 waves (2M x 4N), per-wave (BM/2 x 64). 4 phases per K-tile, each
// computing one 32-col x QR-row quadrant; LDS XOR-16B swizzled (bank-balanced
// ds_read_b128); stage-all at phase 0 (4-phase latency cover); raw s_barrier;
// vmcnt(0) once per K-tile; setprio around MFMA clusters.
template <int BM, int BN, bool RELU, bool BF16OUT>
__global__ __launch_bounds__(512, 2) void k_gemm8(
    const unsigned short* __restrict__ A,   // [M][K] bf16
    const unsigned short* __restrict__ WT,  // [N][K] bf16
    const float* __restrict__ bias,         // [N] fp32
    void* __restrict__ Cv,                  // [M][N] bf16 or fp32
    int M, int N, int K) {
  constexpr int WROWS = BM / 2;    // per-wave rows
  constexpr int QR = WROWS / 2;    // quadrant rows
  constexpr int FMq = QR / 16;     // m-frags per quadrant
  constexpr int ACH = BM / 64;     // 8KB stage chunks for A per K-tile
  constexpr int BCH = BN / 64;

  // XCD-bijective chunk swizzle, y-fastest work order
  const int nby = gridDim.y;
  const int nwg = gridDim.x * nby;
  int orig = blockIdx.x + gridDim.x * blockIdx.y;
  int q = nwg >> 3, r = nwg & 7;
  int xcd = orig & 7, idx = orig >> 3;
  int wg = (xcd < r ? xcd * (q + 1) : r * (q + 1) + (xcd - r) * q) + idx;
  int bx = wg / nby, by = wg % nby;
  const int m0 = bx * BM, n0 = by * BN;

  __shared__ __align__(16) unsigned short As[2][BM * 64];
  __shared__ __align__(16) unsigned short Bs[2][BN * 64];

  const int t = threadIdx.x;
  const int l = t & 63;
  const int w = t >> 6;
  const int wm = w >> 2, wn = w & 3;

  // staging coords: thread t covers byte t*16 of each 8KB chunk (64 rows x 128B)
  const int rl = t >> 3;                 // row within chunk
  const int sl16 = (t & 7) ^ (rl & 7);   // inverse-swizzled 16B slot -> source col
  const unsigned short* asrc[ACH];
  const unsigned short* bsrc[BCH];
#pragma unroll
  for (int i = 0; i < ACH; ++i)
    asrc[i] = A + (size_t)(m0 + i * 64 + rl) * K + sl16 * 8;
#pragma unroll
  for (int i = 0; i < BCH; ++i)
    bsrc[i] = WT + (size_t)(n0 + i * 64 + rl) * K + sl16 * 8;
  const int dst = t * 8;

  auto STAGE = [&](int kt, int buf) {
#pragma unroll
    for (int i = 0; i < ACH; ++i)
      gload16(asrc[i] + kt * 64, &As[buf][i * 4096 + dst]);
#pragma unroll
    for (int i = 0; i < BCH; ++i)
      gload16(bsrc[i] + kt * 64, &Bs[buf][i * 4096 + dst]);
  };

  f32x4 acc[2][2][FMq][2] = {};   // [qm][qn][fm][fn]
  bf16x8 af[FMq][2];              // current qm's A frags [fm][ks]
  bf16x8 bq[2][2][2];             // both qn's B frags [qn][fn][ks]

  const int la = l & 15;
  const int ko = l >> 4;          // 0..3
  const int arow0 = wm * WROWS + la;
  const int brow0 = wn * 64 + la;

  const int nt = K / 64;
  STAGE(0, 0);

  for (int kt = 0; kt < nt; ++kt) {
    const int cur = kt & 1;
    const char* Ab = (const char*)As[cur];
    const char* Bb = (const char*)Bs[cur];

    asm volatile("s_waitcnt vmcnt(0)" ::: "memory");
    __builtin_amdgcn_s_barrier();
    if (kt + 1 < nt) STAGE(kt + 1, cur ^ 1);
    __builtin_amdgcn_sched_barrier(0);

    // ---- phase 0: quadrant (0,0); read A(q0) + B(q0) ----
#pragma unroll
    for (int fm = 0; fm < FMq; ++fm)
#pragma unroll
      for (int ks = 0; ks < 2; ++ks) {
        int row = arow0 + fm * 16;
        int s = ks * 4 + ko;
        af[fm][ks] = *(const bf16x8*)(Ab + (row << 7) + ((s ^ (row & 7)) << 4));
      }
#pragma unroll
    for (int fn = 0; fn < 2; ++fn)
#pragma unroll
      for (int ks = 0; ks < 2; ++ks) {
        int row = brow0 + fn * 16;
        int s = ks * 4 + ko;
        bq[0][fn][ks] = *(const bf16x8*)(Bb + (row << 7) + ((s ^ (row & 7)) << 4));
      }
    __builtin_amdgcn_s_setprio(1);
#pragma unroll
    for (int fm = 0; fm < FMq; ++fm)
#pragma unroll
      for (int fn = 0; fn < 2; ++fn)
#pragma unroll
        for (int ks = 0; ks < 2; ++ks)
          acc[0][0][fm][fn] = __builtin_amdgcn_mfma_f32_16x16x32_bf16(
              af[fm][ks], bq[0][fn][ks], acc[0][0][fm][fn], 0, 0, 0);
    __builtin_amdgcn_s_setprio(0);
    __builtin_amdgcn_s_barrier();

    // ---- phase 1: quadrant (0,1); read B(q1) ----
#pragma unroll
    for (int fn = 0; fn < 2; ++fn)
#pragma unroll
      for (int ks = 0; ks < 2; ++ks) {
        int row = brow0 + 32 + fn * 16;
        int s = ks * 4 + ko;
        bq[1][fn][ks] = *(const bf16x8*)(Bb + (row << 7) + ((s ^ (row & 7)) << 4));
      }
    __builtin_amdgcn_s_setprio(1);
#pragma unroll
    for (int fm = 0; fm < FMq; ++fm)
#pragma unroll
      for (int fn = 0; fn < 2; ++fn)
#pragma unroll
        for (int ks = 0; ks < 2; ++ks)
          acc[0][1][fm][fn] = __builtin_amdgcn_mfma_f32_16x16x32_bf16(
              af[fm][ks], bq[1][fn][ks], acc[0][1][fm][fn], 0, 0, 0);
    __builtin_amdgcn_s_setprio(0);
    __builtin_amdgcn_s_barrier();

    // ---- phase 2: quadrant (1,0); read A(q1) ----
#pragma unroll
    for (int fm = 0; fm < FMq; ++fm)
#pragma unroll
      for (int ks = 0; ks < 2; ++ks) {
        int row = arow0 + QR + fm * 16;
        int s = ks * 4 + ko;
        af[fm][ks] = *(const bf16x8*)(Ab + (row << 7) + ((s ^ (row & 7)) << 4));
      }
    __builtin_amdgcn_s_setprio(1);
#pragma unroll
    for (int fm = 0; fm < FMq; ++fm)
#pragma unroll
      for (int fn = 0; fn < 2; ++fn)
#pragma unroll
        for (int ks = 0; ks < 2; ++ks)
          acc[1][0][fm][fn] = __builtin_amdgcn_mfma_f32_16x16x32_bf16(
              af[fm][ks], bq[0][fn][ks], acc[1][0][fm][fn], 0, 0, 0);
    __builtin_amdgcn_s_setprio(0);
    __builtin_amdgcn_s_barrier();

    // ---- phase 3: quadrant (1,1); no reads ----
    __builtin_amdgcn_s_setprio(1);
#pragma unroll
    for (int fm = 0; fm < FMq; ++fm)
#pragma unroll
      for (int fn = 0; fn < 2; ++fn)
#pragma unroll
        for (int ks = 0; ks < 2; ++ks)
          acc[1][1][fm][fn] = __builtin_amdgcn_mfma_f32_16x16x32_bf16(
              af[fm][ks], bq[1][fn][ks], acc[1][1][fm][fn], 0, 0, 0);
    __builtin_amdgcn_s_setprio(0);
  }
  asm volatile("s_waitcnt vmcnt(0)" ::: "memory");

  // epilogue
  const int crow0 = m0 + wm * WROWS;
  const int ccol0 = n0 + wn * 64;
#pragma unroll
  for (int qn = 0; qn < 2; ++qn)
#pragma unroll
    for (int fn = 0; fn < 2; ++fn) {
      int c = ccol0 + qn * 32 + fn * 16 + la;
      float bv = bias[c];
#pragma unroll
      for (int qm = 0; qm < 2; ++qm)
#pragma unroll
        for (int fm = 0; fm < FMq; ++fm)
#pragma unroll
          for (int j = 0; j < 4; ++j) {
            int rr = crow0 + qm * QR + fm * 16 + (ko << 2) + j;
            float v = acc[qm][qn][fm][fn][j] + bv;
            if (RELU) v = fmaxf(v, 0.0f);
            if (BF16OUT) ((unsigned short*)Cv)[(size_t)rr * N + c] = f2bf(v);
            else         ((float*)Cv)[(size_t)rr * N + c] = v;
          }
    }
}

// ---------------- round-5 GEMM (kept for L2 / grouped experts) ----------------
template <int TBM, int TBN, int WM, int WN,
          bool RELU, bool BF16OUT, bool GROUPED, bool SCATTER, bool GATHER>
__global__ __launch_bounds__(256) void k_gemm(
    const unsigned short* __restrict__ A,
    const unsigned short* __restrict__ WT,
    const float* __restrict__ bias,
    void* __restrict__ Cv,
    int M, int N, int K,
    const int* __restrict__ starts, const int* __restrict__ counts,
    const int* __restrict__ perm) {
  constexpr int FM = TBM / WM / 16;
  constexpr int FN = TBN / WN / 16;
  constexpr int ALOADS = TBM / 64;
  constexpr int BLOADS = TBN / 64;
  constexpr int LDS_LD = ALOADS + BLOADS;

  const int nby = gridDim.y;
  const int nwg = gridDim.x * nby;
  int orig = blockIdx.x + gridDim.x * blockIdx.y;
  int q = nwg >> 3, r = nwg & 7;
  int xcd = orig & 7, idx = orig >> 3;
  int wg = (xcd < r ? xcd * (q + 1) : r * (q + 1) + (xcd - r) * q) + idx;
  int bx = wg / nby, by = wg % nby;

  int Meff, start = 0, mo;
  const unsigned short* Wp = WT;
  const float* biasp = bias;
  if (GROUPED) {
    int bxr = bx;
    int found = 0;
#pragma unroll
    for (int e = 0; e < N_CLS; ++e) {
      int c = counts[e];
      int nb = (c + TBM - 1) / TBM;
      if (!found && bxr < nb) {
        found = 1; Meff = c; start = starts[e]; mo = bxr * TBM;
        Wp = WT + (size_t)e * N * K; biasp = bias + (size_t)e * N;
      }
      if (!found) bxr -= nb;
    }
    if (!found) return;
    if (!GATHER) A += (size_t)start * K;
  } else {
    Meff = M; mo = bx * TBM;
  }
  const int n0 = by * TBN;

  __shared__ __align__(16) unsigned short As[3][TBM * 32];
  __shared__ __align__(16) unsigned short Bs[3][TBN * 32];

  const int t = threadIdx.x;
  const int l = t & 63;
  const int w = t >> 6;
  const int wm = (w / WN) * (TBM / WM);
  const int wn = (w % WN) * (TBN / WN);

  const int srow = t >> 2;
  const int scol = (t & 3) * 8;
  const unsigned short* ag[ALOADS];
  const unsigned short* bg[BLOADS];
#pragma unroll
  for (int i = 0; i < ALOADS; ++i) {
    int arow = mo + srow + i * 64;
    if (GROUPED) arow = arow < Meff ? arow : Meff - 1;
    int srcrow = GATHER ? perm[start + arow] : arow;
    ag[i] = A + (size_t)srcrow * K + scol;
  }
#pragma unroll
  for (int i = 0; i < BLOADS; ++i)
    bg[i] = Wp + (size_t)(n0 + srow + i * 64) * K + scol;

  auto STAGE = [&](int buf) {
#pragma unroll
    for (int i = 0; i < ALOADS; ++i) {
      gload16(ag[i], &As[buf][t * 8 + i * 2048]);
      ag[i] += 32;
    }
#pragma unroll
    for (int i = 0; i < BLOADS; ++i) {
      gload16(bg[i], &Bs[buf][t * 8 + i * 2048]);
      bg[i] += 32;
    }
  };

  f32x4 acc[FM][FN] = {};

  const int nt = K / 32;
  STAGE(0);
  STAGE(1);
  for (int tI = 0; tI < nt; ++tI) {
    if (tI + 1 < nt)
      asm volatile("s_waitcnt vmcnt(%0)" :: "i"(LDS_LD) : "memory");
    else
      asm volatile("s_waitcnt vmcnt(0)" ::: "memory");
    __builtin_amdgcn_s_barrier();
    __builtin_amdgcn_sched_barrier(0);
    if (tI + 2 < nt) STAGE((tI + 2) % 3);

    const int cur = tI % 3;
    bf16x8 af[FM], bfr[FN];
#pragma unroll
    for (int i = 0; i < FM; ++i)
      af[i] = *(const bf16x8*)(&As[cur][(wm + i * 16 + (l & 15)) * 32 + (l >> 4) * 8]);
#pragma unroll
    for (int i = 0; i < FN; ++i)
      bfr[i] = *(const bf16x8*)(&Bs[cur][(wn + i * 16 + (l & 15)) * 32 + (l >> 4) * 8]);
#pragma unroll
    for (int mi = 0; mi < FM; ++mi)
#pragma unroll
      for (int ni = 0; ni < FN; ++ni)
        acc[mi][ni] = __builtin_amdgcn_mfma_f32_16x16x32_bf16(af[mi], bfr[ni], acc[mi][ni], 0, 0, 0);
  }

  const int cb = n0 + wn + (l & 15);
#pragma unroll
  for (int ni = 0; ni < FN; ++ni) {
    int c = cb + ni * 16;
    float bv = biasp[c];
#pragma unroll
    for (int mi = 0; mi < FM; ++mi) {
#pragma unroll
      for (int j = 0; j < 4; ++j) {
        int rl2 = wm + mi * 16 + ((l >> 4) << 2) + j;
        int re = mo + rl2;
        if (GROUPED && re >= Meff) continue;
        float v = acc[mi][ni][j] + bv;
        if (RELU) v = fmaxf(v, 0.0f);
        int orow;
        if (SCATTER)      orow = perm[start + re];
        else if (GROUPED) orow = start + re;
        else              orow = re;
        if (BF16OUT) ((unsigned short*)Cv)[(size_t)orow * N + c] = f2bf(v);
        else         ((float*)Cv)[(size_t)orow * N + c] = v;
      }
    }
  }
}

#define GX_GROUPED 74   // worst-case sum of ceil(counts[e]/128) over 10 experts

// ---------------- launch ----------------
extern "C" void kernel_launch(void* const* d_in, const int* in_sizes, int n_in,
                              void* d_out, int out_size, void* d_ws, size_t ws_size,
                              hipStream_t stream) {
  const float* x      = (const float*)d_in[0];
  const int*   labels = (const int*)d_in[1];
  const float* W1  = (const float*)d_in[2];  const float* b1  = (const float*)d_in[3];
  const float* W2  = (const float*)d_in[4];  const float* b2  = (const float*)d_in[5];
  const float* EW1 = (const float*)d_in[6];  const float* Eb1 = (const float*)d_in[7];
  const float* EW2 = (const float*)d_in[8];  const float* Eb2 = (const float*)d_in[9];
  const float* DW1 = (const float*)d_in[10]; const float* Db1 = (const float*)d_in[11];
  const float* DW2 = (const float*)d_in[12]; const float* Db2 = (const float*)d_in[13];
  float* out = (float*)d_out;

  char* ws = (char*)d_ws;
  size_t o = 0;
  unsigned short* W1T  = (unsigned short*)(ws + o); o += (size_t)D_IN * D_H * 2;
  unsigned short* W2T  = (unsigned short*)(ws + o); o += (size_t)D_H * D_BOT * 2;
  unsigned short* EW1T = (unsigned short*)(ws + o); o += (size_t)N_CLS * D_BOT * D_EXP * 2;
  unsigned short* EW2T = (unsigned short*)(ws + o); o += (size_t)N_CLS * D_EXP * D_BOT * 2;
  unsigned short* DW1T = (unsigned short*)(ws + o); o += (size_t)D_BOT * D_H * 2;
  unsigned short* DW2T = (unsigned short*)(ws + o); o += (size_t)D_H * D_IN * 2;
  unsigned short* xb   = (unsigned short*)(ws + o); o += (size_t)Bsz * D_IN * 2;
  unsigned short* e1p  = xb;                         // alias: xb dead after L1
  unsigned short* actA = (unsigned short*)(ws + o); o += (size_t)Bsz * D_H * 2;
  unsigned short* h2   = (unsigned short*)(ws + o); o += (size_t)Bsz * D_BOT * 2;
  unsigned short* sel  = (unsigned short*)(ws + o); o += (size_t)Bsz * D_BOT * 2;
  int* counts = (int*)(ws + o);
  int* starts = counts + 16;
  int* perm   = counts + 64;

  // routing metadata (single block)
  k_route<<<1, 1024, 0, stream>>>(labels, counts, starts, perm);

  // conversions
  k_cvt<<<(Bsz * D_IN) / (256 * 8), 256, 0, stream>>>(x, xb);
  k_transpose_cvt<<<dim3(D_H / 32, D_IN / 32, 1),  dim3(32, 8), 0, stream>>>(W1, W1T, D_IN, D_H);
  k_transpose_cvt<<<dim3(D_BOT / 32, D_H / 32, 1), dim3(32, 8), 0, stream>>>(W2, W2T, D_H, D_BOT);
  k_transpose_cvt<<<dim3(D_EXP / 32, D_BOT / 32, N_CLS), dim3(32, 8), 0, stream>>>(EW1, EW1T, D_BOT, D_EXP);
  k_transpose_cvt<<<dim3(D_BOT / 32, D_EXP / 32, N_CLS), dim3(32, 8), 0, stream>>>(EW2, EW2T, D_EXP, D_BOT);
  k_transpose_cvt<<<dim3(D_H / 32, D_BOT / 32, 1), dim3(32, 8), 0, stream>>>(DW1, DW1T, D_BOT, D_H);
  k_transpose_cvt<<<dim3(D_IN / 32, D_H / 32, 1),  dim3(32, 8), 0, stream>>>(DW2, DW2T, D_H, D_IN);

  // encoder
  k_gemm8<256, 256, true, true><<<dim3(Bsz / 256, D_H / 256), 512, 0, stream>>>(
      xb, W1T, b1, actA, Bsz, D_H, D_IN);
  k_gemm<128, 64, 4, 1, true, true, false, false, false><<<dim3(Bsz / 128, D_BOT / 64), 256, 0, stream>>>(
      actA, W2T, b2, h2, Bsz, D_BOT, D_H, nullptr, nullptr, nullptr);

  // routed experts; E1 gathers A rows via perm during staging, E2 scatters back
  k_gemm<128, 128, 2, 2, true, true, true, false, true><<<dim3(GX_GROUPED, D_EXP / 128), 256, 0, stream>>>(
      h2, EW1T, Eb1, e1p, Bsz, D_EXP, D_BOT, starts, counts, perm);
  k_gemm<128, 64, 4, 1, true, true, true, true, false><<<dim3(GX_GROUPED, D_BOT / 64), 256, 0, stream>>>(
      e1p, EW2T, Eb2, sel, Bsz, D_BOT, D_EXP, starts, counts, perm);

  // decoder
  k_gemm8<256, 256, true, true><<<dim3(Bsz / 256, D_H / 256), 512, 0, stream>>>(
      sel, DW1T, Db1, actA, Bsz, D_H, D_BOT);
  k_gemm8<128, 256, false, false><<<dim3(Bsz / 128, D_IN / 256), 512, 0, stream>>>(
      actA, DW2T, Db2, out, Bsz, D_IN, D_H);
}